// Round 6
// baseline (2840.928 us; speedup 1.0000x reference)
//
#include <hip/hip_runtime.h>

typedef unsigned short u16;
typedef unsigned int u32;
typedef float f32x16 __attribute__((ext_vector_type(16)));
typedef float f32x4v __attribute__((ext_vector_type(4)));
typedef unsigned int u32x4 __attribute__((ext_vector_type(4)));
typedef unsigned int u32x2 __attribute__((ext_vector_type(2)));

#define TT 512
#define NBLK 64

// ---- ws layout (bytes) ----
static const size_t OFF_EMBX = 0;          // u16 [512][64][192]  = 12,582,912
static const size_t OFF_HS   = 12582912;   // u16 [512][64][1024] = 67,108,864
static const size_t OFF_HBUF = 79691776;   // u16 [dir][par][64 b][512 k] = 262,144
static const size_t OFF_BAR  = 79953920;   // int flags[2][64] (512 B, zeroed each launch)
static const size_t OFF_FEAT = 79954176;   // f32 [512*64][10]    = 1,310,720
static const size_t OFF_RES  = 81264896;   // f32 [64]
static const size_t WS_NEED  = 81265152;

__device__ inline u32 packbf(float a, float b) {
  u32 ua = __float_as_uint(a); ua += 0x7fffu + ((ua >> 16) & 1u);
  u32 ub = __float_as_uint(b); ub += 0x7fffu + ((ub >> 16) & 1u);
  return (ua >> 16) | (ub & 0xffff0000u);
}
__device__ inline u16 f2b(float a) {
  u32 u = __float_as_uint(a); u += 0x7fffu + ((u >> 16) & 1u);
  return (u16)(u >> 16);
}
__device__ inline float sigm(float x) { return 1.f / (1.f + __expf(-x)); }
__device__ inline float tanhx(float x) {
  float e = __expf(-2.f * fabsf(x));
  float t = (1.f - e) / (1.f + e);
  return (x < 0.f) ? -t : t;
}

// Consumer loads: L1/L2-bypassing, read at device coherence point
__device__ inline u32x4 ldg_cc(const u16* p) {
  u32x4 r;
  asm volatile("global_load_dwordx4 %0, %1, off sc0 sc1"
               : "=v"(r) : "v"(p) : "memory");
  return r;
}
__device__ inline int ldflag(const int* p) {
  int r;
  asm volatile("global_load_dword %0, %1, off sc0 sc1"
               : "=v"(r) : "v"(p) : "memory");
  asm volatile("s_waitcnt vmcnt(0)" ::: "memory");
  return r;
}
// Producer stores: device-scope ATOMICS -> execute at coherence point and
// keep the line resident there (L3), so consumer loads are L3 hits.
__device__ inline void stg_at8(u16* p, u32x2 v) {
  asm volatile("global_atomic_swap_x2 %0, %1, off sc1"
               :: "v"(p), "v"(v) : "memory");
}
__device__ inline void stflag_at(int* p, int v) {
  asm volatile("global_atomic_swap %0, %1, off sc1"
               :: "v"(p), "v"(v) : "memory");
}

// ---- 1. embedding gather: embX[t][b][0..191] bf16 ----
__global__ __launch_bounds__(256) void k_embed(const int* __restrict__ bdata,
                                               const int* __restrict__ brad,
                                               const float* __restrict__ cemb,
                                               const float* __restrict__ remb,
                                               u16* __restrict__ embX) {
  int t = blockIdx.x;
  int tid = threadIdx.x;
#pragma unroll
  for (int r = 0; r < 6; ++r) {
    int cc = r * 256 + tid;           // 0..1535 = 64 b * 24 chunks
    int b = cc / 24;
    int j = cc - b * 24;              // chunk of 8 floats
    int ic = bdata[b * TT + t];
    int ir = brad[b * TT + t];
    const float* src = (j < 16) ? (cemb + (size_t)ic * 128 + j * 8)
                                : (remb + (size_t)ir * 64 + (j - 16) * 8);
    f32x4v f0 = *(const f32x4v*)src;
    f32x4v f1 = *(const f32x4v*)(src + 4);
    u32x4 o;
    o[0] = packbf(f0[0], f0[1]); o[1] = packbf(f0[2], f0[3]);
    o[2] = packbf(f1[0], f1[1]); o[3] = packbf(f1[2], f1[3]);
    *(u32x4*)(embX + ((size_t)t * 64 + b) * 192 + j * 8) = o;
  }
}

// ---- 2. persistent bidirectional LSTM ----
// 64 blocks: blk>>5 = dir, (blk&31)*16 = hidden slice j0. 256 thr = 4 waves.
// h exchanged transposed [b][k]: atomic-swap stores (L3-resident) + cc loads.
// A-row map gate*512+j0+(l31&7)+8m => thread's acc = i,f,g,o x 4 consecutive j
// for ONE batch column -> pointwise entirely in registers.
__global__ __launch_bounds__(256, 1) void k_lstm(
    const u16* __restrict__ embX, u16* __restrict__ hbuf, u16* __restrict__ hs,
    const float* __restrict__ wihf, const float* __restrict__ whhf, const float* __restrict__ bf,
    const float* __restrict__ wihb, const float* __restrict__ whhb, const float* __restrict__ bb,
    int* __restrict__ flags) {
  __shared__ u16 smh[64 * 512];          // h staged as [b][512 k^swz]   (64 KB)
  __shared__ u16 hl[64 * 16];            // h-out bounce [b][16]         (2 KB)

  const int tid = threadIdx.x;
  const int lane = tid & 63;
  const int wid = tid >> 6;
  const int blk = blockIdx.x;
  const int dir = blk >> 5;
  const int j0 = (blk & 31) << 4;

  const float* wih = dir ? wihb : wihf;
  const float* whh = dir ? whhb : whhf;
  const float* bias = dir ? bb : bf;

  const int m = wid >> 1, n = wid & 1;
  const int l31 = lane & 31;
  const int hi = lane >> 5;

  // A-operand (weights) -> registers, once.
  // A row (within 32-tile) = l31; gate = l31>>3; jloc = (l31&7) + 8*m
  const int gate = l31 >> 3;
  const int jloc = (l31 & 7) + 8 * m;
  const int grow = gate * 512 + j0 + jloc;
  const float* pih = wih + (size_t)grow * 192 + 8 * hi;
  const float* phh = whh + (size_t)grow * 512 + 8 * hi;
  u32x4 aw[44];
#pragma unroll
  for (int kt = 0; kt < 44; ++kt) {
    const float* p = (kt < 12) ? (pih + kt * 16) : (phh + (kt - 12) * 16);
    f32x4v f0 = *(const f32x4v*)p;
    f32x4v f1 = *(const f32x4v*)(p + 4);
    u32x4 a;
    a[0] = packbf(f0[0], f0[1]); a[1] = packbf(f0[2], f0[3]);
    a[2] = packbf(f1[0], f1[1]); a[3] = packbf(f1[2], f1[3]);
    aw[kt] = a;
  }

  u16* hb_dT = hbuf + dir * 65536;       // [2 parity][64 b][512 k]

  const int bb_ = n * 32 + l31;          // batch column for B-frags
  const int swzr = (bb_ & 15) << 4;      // byte swizzle within 1KB row
  const char* hbase = (const char*)smh + bb_ * 1024;
  const int hoff = hi * 16;

  // pointwise: this thread owns (b = bb_, j = j0 + 8m + 4hi + q), q=0..3
  const int jme = j0 + 8 * m + 4 * hi;
  float creg[4] = {0.f, 0.f, 0.f, 0.f};
  float bI[4], bF[4], bG[4], bO[4];
#pragma unroll
  for (int q = 0; q < 4; ++q) {
    bI[q] = bias[jme + q];
    bF[q] = bias[512 + jme + q];
    bG[q] = bias[1024 + jme + q];
    bO[q] = bias[1536 + jme + q];
  }

  int* myflags = flags + dir * 64;       // 32 flags, 8B apart (256 B / dir)

  for (int t = 0; t < TT; ++t) {
    const int par = t & 1;
    const int tx = dir ? (511 - t) : t;

    // ---- x-fragment prefetch (independent of other blocks; hides under poll)
    u32x4 xf[12];
    const u16* xbase = embX + ((size_t)tx * 64 + bb_) * 192 + 8 * hi;
#pragma unroll
    for (int kt = 0; kt < 12; ++kt) xf[kt] = *(const u32x4*)(xbase + kt * 16);

    // ---- wait for h(t-1): wave 0 gathers all 32 producer flags in one load
    if (t) {
      if (wid == 0) {
        int f = ldflag(myflags + (lane & 31) * 2);
        int guard = 0;
        while (__any(f < t)) {
          if (++guard > 200000) break;  // failsafe: wrong answer > hang
          f = ldflag(myflags + (lane & 31) * 2);
        }
      }
      __syncthreads();
    }

    // ---- stage h_T: 16 loads -> ONE vmcnt(0) -> 16 LDS writes (single RT)
    {
      const u16* src = hb_dT + par * 32768;
      u32x4 v[16];
#pragma unroll
      for (int r = 0; r < 16; ++r) {
        int b = r * 4 + wid;
        v[r] = ldg_cc(src + b * 512 + lane * 8);
      }
      asm volatile("s_waitcnt vmcnt(0)" ::: "memory");
#pragma unroll
      for (int r = 0; r < 16; ++r) {
        int b = r * 4 + wid;
        int kk = (lane * 8) ^ ((b & 15) << 3);
        *(u32x4*)(smh + b * 512 + kk) = v[r];
      }
    }
    __syncthreads();

    // ---- MFMA: acc rows = gates (i,f,g,o x j), cols = batch; K=512(h)+192(x)
    f32x16 acc;
#pragma unroll
    for (int i = 0; i < 16; ++i) acc[i] = 0.f;
    asm volatile("s_nop 7\ns_nop 7");
#pragma unroll
    for (int kt = 0; kt < 32; ++kt) {
      u32x4 bfrag = *(const u32x4*)(hbase + ((kt * 32 + hoff) ^ swzr));
      asm("v_mfma_f32_32x32x16_bf16 %0, %1, %2, %0" : "+v"(acc) : "v"(aw[kt]), "v"(bfrag));
    }
#pragma unroll
    for (int kt = 0; kt < 12; ++kt) {
      asm("v_mfma_f32_32x32x16_bf16 %0, %1, %2, %0" : "+v"(acc) : "v"(aw[32 + kt]), "v"(xf[kt]));
    }
    asm volatile("s_nop 7\ns_nop 7\ns_nop 7");

    // ---- pointwise LSTM cell directly on accumulators
    // acc[q]=i, acc[4+q]=f, acc[8+q]=g, acc[12+q]=o for j=jme+q, b=bb_
    {
      u16* dstT = hb_dT + (par ^ 1) * 32768;
      u32 hp0 = 0, hp1 = 0;
#pragma unroll
      for (int q = 0; q < 4; ++q) {
        float gi = acc[q] + bI[q];
        float gf = acc[4 + q] + bF[q];
        float gg = acc[8 + q] + bG[q];
        float go = acc[12 + q] + bO[q];
        float cn = sigm(gf) * creg[q] + sigm(gi) * tanhx(gg);
        creg[q] = cn;
        float h = sigm(go) * tanhx(cn);
        u32 h16 = (u32)f2b(h);
        if (q == 0) hp0 = h16;
        else if (q == 1) hp0 |= h16 << 16;
        else if (q == 2) hp1 = h16;
        else hp1 |= h16 << 16;
      }
      u32x2 hv; hv[0] = hp0; hv[1] = hp1;
      stg_at8(dstT + bb_ * 512 + jme, hv);   // L3-resident atomic store
      *(u32x2*)(hl + bb_ * 16 + (jme - j0)) = hv;
    }

    // ---- drain h atomics, block barrier, publish flag + coalesced hs store
    asm volatile("s_waitcnt vmcnt(0)" ::: "memory");
    __syncthreads();
    if (t != TT - 1 && tid == 0) stflag_at(myflags + (blk & 31) * 2, t + 1);
    if (tid < 128) {
      int ob = tid >> 1, hf = tid & 1;
      u32x4 v = *(const u32x4*)(hl + ob * 16 + hf * 8);
      *(u32x4*)(hs + ((size_t)tx * 64 + ob) * 1024 + dir * 512 + j0 + hf * 8) = v;
    }
  }
}

// ---- 3. emission: feats[row=t*64+b][c] = hs_row . w_cls[c] + b_cls[c] ----
__global__ __launch_bounds__(256) void k_emis(const u16* __restrict__ hs,
                                              const float* __restrict__ wcls,
                                              const float* __restrict__ bcls,
                                              float* __restrict__ feats) {
  __shared__ float wl[10240];
  int tid = threadIdx.x;
  for (int i = tid; i < 10240; i += 256) wl[i] = wcls[i];
  __syncthreads();
  int row = blockIdx.x * 256 + tid;
  const u16* hrow = hs + (size_t)row * 1024;
  float acc[10];
#pragma unroll
  for (int c = 0; c < 10; ++c) acc[c] = bcls[c];
  for (int k0 = 0; k0 < 1024; k0 += 8) {
    u32x4 v = *(const u32x4*)(hrow + k0);
    float x0 = __uint_as_float(v[0] << 16);
    float x1 = __uint_as_float(v[0] & 0xffff0000u);
    float x2 = __uint_as_float(v[1] << 16);
    float x3 = __uint_as_float(v[1] & 0xffff0000u);
    float x4 = __uint_as_float(v[2] << 16);
    float x5 = __uint_as_float(v[2] & 0xffff0000u);
    float x6 = __uint_as_float(v[3] << 16);
    float x7 = __uint_as_float(v[3] & 0xffff0000u);
#pragma unroll
    for (int c = 0; c < 10; ++c) {
      const float* w = &wl[c * 1024 + k0];
      f32x4v wa = *(const f32x4v*)w;
      f32x4v wb = *(const f32x4v*)(w + 4);
      acc[c] += x0 * wa[0] + x1 * wa[1] + x2 * wa[2] + x3 * wa[3] +
                x4 * wb[0] + x5 * wb[1] + x6 * wb[2] + x7 * wb[3];
    }
  }
#pragma unroll
  for (int c = 0; c < 10; ++c) feats[(size_t)row * 10 + c] = acc[c];
}

// ---- 4. CRF forward + gold score, one wave per batch element ----
__global__ void k_crf(const float* __restrict__ feats, const float* __restrict__ trans,
                      const int* __restrict__ btag, float* __restrict__ res) {
  int b = blockIdx.x;
  int lane = threadIdx.x;
  float tr[10];
  int to = lane < 10 ? lane : 9;
#pragma unroll
  for (int f = 0; f < 10; ++f) tr[f] = trans[to * 10 + f];
  float al[10];
#pragma unroll
  for (int f = 0; f < 10; ++f) al[f] = (f == 8) ? 0.f : -10000.f;  // START_ID=8
  float fe_next = (lane < 10) ? feats[(size_t)b * 10 + lane] : 0.f;
  for (int t = 0; t < 512; ++t) {
    float fe = fe_next;
    if (t < 511)
      fe_next = (lane < 10) ? feats[((size_t)(t + 1) * 64 + b) * 10 + lane] : 0.f;
    float mx = -3.0e38f;
#pragma unroll
    for (int f = 0; f < 10; ++f) mx = fmaxf(mx, al[f] + tr[f]);
    float s = 0.f;
#pragma unroll
    for (int f = 0; f < 10; ++f) s += __expf(al[f] + tr[f] - mx);
    float an = mx + __logf(s) + fe;
#pragma unroll
    for (int f = 0; f < 10; ++f) al[f] = __shfl(an, f);
  }
  float mx = -3.0e38f;
#pragma unroll
  for (int f = 0; f < 10; ++f) mx = fmaxf(mx, al[f]);
  float s = 0.f;
#pragma unroll
  for (int f = 0; f < 10; ++f) s += __expf(al[f] - mx);
  float fwd = mx + __logf(s);
  // gold score
  float g = 0.f;
  for (int t = lane; t < 512; t += 64) {
    int tg = btag[b * 512 + t];
    int pv = (t == 0) ? 8 : btag[b * 512 + t - 1];
    g += trans[tg * 10 + pv] + feats[((size_t)t * 64 + b) * 10 + tg];
  }
#pragma unroll
  for (int off = 32; off > 0; off >>= 1) g += __shfl_down(g, off);
  if (lane == 0) res[b] = fwd - g;
}

// ---- 5. final reduce ----
__global__ void k_fin(const float* __restrict__ res, float* __restrict__ out) {
  float v = res[threadIdx.x];
#pragma unroll
  for (int off = 32; off > 0; off >>= 1) v += __shfl_down(v, off);
  if (threadIdx.x == 0) out[0] = v * (1.f / 64.f);
}

extern "C" void kernel_launch(void* const* d_in, const int* in_sizes, int n_in,
                              void* d_out, int out_size, void* d_ws, size_t ws_size,
                              hipStream_t stream) {
  (void)in_sizes; (void)n_in; (void)out_size;
  if (ws_size < WS_NEED) return;  // visible failure instead of OOB

  const int* bdata = (const int*)d_in[0];
  const int* brad  = (const int*)d_in[1];
  const int* btag  = (const int*)d_in[2];
  const float* cemb = (const float*)d_in[3];
  const float* remb = (const float*)d_in[4];
  const float* wihf = (const float*)d_in[5];
  const float* whhf = (const float*)d_in[6];
  const float* bf   = (const float*)d_in[7];
  const float* wihb = (const float*)d_in[8];
  const float* whhb = (const float*)d_in[9];
  const float* bb   = (const float*)d_in[10];
  const float* wcls = (const float*)d_in[11];
  const float* bcls = (const float*)d_in[12];
  const float* trans = (const float*)d_in[13];

  char* ws = (char*)d_ws;
  u16* embX = (u16*)(ws + OFF_EMBX);
  u16* hs   = (u16*)(ws + OFF_HS);
  u16* hbuf = (u16*)(ws + OFF_HBUF);
  int* flags = (int*)(ws + OFF_BAR);
  float* feats = (float*)(ws + OFF_FEAT);
  float* res = (float*)(ws + OFF_RES);

  // zero h0 (both dirs, both parities) + ready-flags, every launch
  hipMemsetAsync(ws + OFF_HBUF, 0, 262144 + 512, stream);

  k_embed<<<512, 256, 0, stream>>>(bdata, brad, cemb, remb, embX);
  k_lstm<<<64, 256, 0, stream>>>(embX, hbuf, hs, wihf, whhf, bf, wihb, whhb, bb, flags);
  k_emis<<<128, 256, 0, stream>>>(hs, wcls, bcls, feats);
  k_crf<<<64, 64, 0, stream>>>(feats, trans, btag, res);
  k_fin<<<1, 64, 0, stream>>>(res, (float*)d_out);
}

// Round 7
// 2592.629 us; speedup vs baseline: 1.0958x; 1.0958x over previous
//
#include <hip/hip_runtime.h>

typedef unsigned short u16;
typedef unsigned int u32;
typedef float f32x16 __attribute__((ext_vector_type(16)));
typedef float f32x4v __attribute__((ext_vector_type(4)));
typedef unsigned int u32x4 __attribute__((ext_vector_type(4)));
typedef unsigned int u32x2 __attribute__((ext_vector_type(2)));

#define TT 512

// ---- ws layout (bytes) ----
static const size_t OFF_EMBX = 0;          // u16 [512][64][192]  = 12,582,912
static const size_t OFF_HS   = 12582912;   // u16 [512][64][1024] = 67,108,864
static const size_t OFF_HBUF = 79691776;   // u16 [dir][par][64 b][512 k] = 262,144
static const size_t OFF_BAR  = 79953920;   // int flags[2][64] (512B) + claim[2] (zeroed)
static const size_t OFF_FEAT = 79954176;   // f32 [512*64][10]    = 1,310,720
static const size_t OFF_RES  = 81264896;   // f32 [64]
static const size_t WS_NEED  = 81265152;

__device__ inline u32 packbf(float a, float b) {
  u32 ua = __float_as_uint(a); ua += 0x7fffu + ((ua >> 16) & 1u);
  u32 ub = __float_as_uint(b); ub += 0x7fffu + ((ub >> 16) & 1u);
  return (ua >> 16) | (ub & 0xffff0000u);
}
__device__ inline float sigm(float x) { return 1.f / (1.f + __expf(-x)); }
__device__ inline float tanhx(float x) {
  float e = __expf(-2.f * fabsf(x));
  float t = (1.f - e) / (1.f + e);
  return (x < 0.f) ? -t : t;
}

// XCD-local exchange helpers: sc0 = bypass L1, hit own XCD's L2 (same TCC for
// all CUs on the XCD). No sc1 -> no L3/HBM writethrough on the critical path.
__device__ inline u32x4 ldg_l2(const u16* p) {
  u32x4 r;
  asm volatile("global_load_dwordx4 %0, %1, off sc0"
               : "=v"(r) : "v"(p) : "memory");
  return r;
}
__device__ inline void stg8_l2(u16* p, u32x2 v) {
  asm volatile("global_store_dwordx2 %0, %1, off sc0"
               :: "v"(p), "v"(v) : "memory");
}
__device__ inline int ldflag(const int* p) {
  int r;
  asm volatile("global_load_dword %0, %1, off sc0"
               : "=v"(r) : "v"(p) : "memory");
  asm volatile("s_waitcnt vmcnt(0)" ::: "memory");
  return r;
}
__device__ inline void stflag(int* p, int v) {
  asm volatile("global_store_dword %0, %1, off sc0"
               :: "v"(p), "v"(v) : "memory");
}

// ---- 1. embedding gather: embX[t][b][0..191] bf16 ----
__global__ __launch_bounds__(256) void k_embed(const int* __restrict__ bdata,
                                               const int* __restrict__ brad,
                                               const float* __restrict__ cemb,
                                               const float* __restrict__ remb,
                                               u16* __restrict__ embX) {
  int t = blockIdx.x;
  int tid = threadIdx.x;
#pragma unroll
  for (int r = 0; r < 6; ++r) {
    int cc = r * 256 + tid;           // 0..1535 = 64 b * 24 chunks
    int b = cc / 24;
    int j = cc - b * 24;              // chunk of 8 floats
    int ic = bdata[b * TT + t];
    int ir = brad[b * TT + t];
    const float* src = (j < 16) ? (cemb + (size_t)ic * 128 + j * 8)
                                : (remb + (size_t)ir * 64 + (j - 16) * 8);
    f32x4v f0 = *(const f32x4v*)src;
    f32x4v f1 = *(const f32x4v*)(src + 4);
    u32x4 o;
    o[0] = packbf(f0[0], f0[1]); o[1] = packbf(f0[2], f0[3]);
    o[2] = packbf(f1[0], f1[1]); o[3] = packbf(f1[2], f1[3]);
    *(u32x4*)(embX + ((size_t)t * 64 + b) * 192 + j * 8) = o;
  }
}

// ---- 2. persistent bidirectional LSTM, XCD-pinned ----
// dir = XCC_ID (0->fwd on XCD0, 1->bwd on XCD1); 32 worker blocks/dir claim
// hidden slices via atomicAdd; all other blocks exit. h exchanged transposed
// [b][k] through the XCD's own L2 (sc0); per-producer flags, same L2.
__global__ __launch_bounds__(256, 1) void k_lstm(
    const u16* __restrict__ embX, u16* __restrict__ hbuf, u16* __restrict__ hs,
    const float* __restrict__ wihf, const float* __restrict__ whhf, const float* __restrict__ bf,
    const float* __restrict__ wihb, const float* __restrict__ whhb, const float* __restrict__ bb,
    int* __restrict__ flags) {
  __shared__ u16 smh[64 * 512];          // h staged as [b][512 k^swz]   (64 KB)
  __shared__ u16 hl[64 * 16];            // h-out bounce [b][16]         (2 KB)
  __shared__ int s_slot;

  const int tid = threadIdx.x;

  int xcd;
  asm volatile("s_getreg_b32 %0, hwreg(20, 0, 32)" : "=s"(xcd));  // HW_REG_XCC_ID
  xcd &= 15;
  if (xcd >= 2) return;                  // only XCD0/XCD1 work
  const int dir = xcd;

  int* claim = flags + 128;              // 2 ints at OFF_BAR+512 (zeroed)
  if (tid == 0) s_slot = atomicAdd(&claim[dir], 1);
  __syncthreads();
  const int slot = s_slot;
  if (slot >= 32) return;                // surplus blocks on this XCD exit
  const int j0 = slot << 4;

  const int lane = tid & 63;
  const int wid = tid >> 6;

  const float* wih = dir ? wihb : wihf;
  const float* whh = dir ? whhb : whhf;
  const float* bias = dir ? bb : bf;

  const int m = wid >> 1, n = wid & 1;
  const int l31 = lane & 31;
  const int hi = lane >> 5;

  // A-operand (weights) -> registers, once.
  // A row (within 32-tile) = l31; gate = l31>>3; jloc = (l31&7) + 8*m
  const int gate = l31 >> 3;
  const int jloc = (l31 & 7) + 8 * m;
  const int grow = gate * 512 + j0 + jloc;
  const float* pih = wih + (size_t)grow * 192 + 8 * hi;
  const float* phh = whh + (size_t)grow * 512 + 8 * hi;
  u32x4 aw[44];
#pragma unroll
  for (int kt = 0; kt < 44; ++kt) {
    const float* p = (kt < 12) ? (pih + kt * 16) : (phh + (kt - 12) * 16);
    f32x4v f0 = *(const f32x4v*)p;
    f32x4v f1 = *(const f32x4v*)(p + 4);
    u32x4 a;
    a[0] = packbf(f0[0], f0[1]); a[1] = packbf(f0[2], f0[3]);
    a[2] = packbf(f1[0], f1[1]); a[3] = packbf(f1[2], f1[3]);
    aw[kt] = a;
  }

  u16* hb_dT = hbuf + dir * 65536;       // [2 parity][64 b][512 k]

  const int bb_ = n * 32 + l31;          // batch column for B-frags
  const int swzr = (bb_ & 15) << 4;      // byte swizzle within 1KB row
  const char* hbase = (const char*)smh + bb_ * 1024;
  const int hoff = hi * 16;

  // pointwise: this thread owns (b = bb_, j = j0 + 8m + 4hi + q), q=0..3
  const int jme = j0 + 8 * m + 4 * hi;
  float creg[4] = {0.f, 0.f, 0.f, 0.f};
  float bI[4], bF[4], bG[4], bO[4];
#pragma unroll
  for (int q = 0; q < 4; ++q) {
    bI[q] = bias[jme + q];
    bF[q] = bias[512 + jme + q];
    bG[q] = bias[1024 + jme + q];
    bO[q] = bias[1536 + jme + q];
  }

  int* myflags = flags + dir * 64;       // 32 flags, 8B apart (256 B / dir)

  for (int t = 0; t < TT; ++t) {
    const int par = t & 1;
    const int tx = dir ? (511 - t) : t;

    // ---- x-fragment prefetch (plain cached; latency hides under poll)
    u32x4 xf[12];
    const u16* xbase = embX + ((size_t)tx * 64 + bb_) * 192 + 8 * hi;
#pragma unroll
    for (int kt = 0; kt < 12; ++kt) xf[kt] = *(const u32x4*)(xbase + kt * 16);

    // ---- wait for h(t-1): wave 0 gathers all 32 producer flags (own L2)
    if (t) {
      if (wid == 0) {
        int f = ldflag(myflags + (lane & 31) * 2);
        int guard = 0;
        while (__any(f < t)) {
          if (++guard > 400000) break;  // failsafe: wrong answer > hang
          f = ldflag(myflags + (lane & 31) * 2);
        }
      }
      __syncthreads();
    }

    // ---- stage h_T: 16 L2 loads -> ONE vmcnt(0) -> 16 LDS writes
    {
      const u16* src = hb_dT + par * 32768;
      u32x4 v[16];
#pragma unroll
      for (int r = 0; r < 16; ++r) {
        int b = r * 4 + wid;
        v[r] = ldg_l2(src + b * 512 + lane * 8);
      }
      asm volatile("s_waitcnt vmcnt(0)" ::: "memory");
#pragma unroll
      for (int r = 0; r < 16; ++r) {
        int b = r * 4 + wid;
        int kk = (lane * 8) ^ ((b & 15) << 3);
        *(u32x4*)(smh + b * 512 + kk) = v[r];
      }
    }
    __syncthreads();

    // ---- MFMA: acc rows = gates (i,f,g,o x j), cols = batch; K=512(h)+192(x)
    f32x16 acc;
#pragma unroll
    for (int i = 0; i < 16; ++i) acc[i] = 0.f;
    asm volatile("s_nop 7\ns_nop 7");
#pragma unroll
    for (int kt = 0; kt < 32; ++kt) {
      u32x4 bfrag = *(const u32x4*)(hbase + ((kt * 32 + hoff) ^ swzr));
      asm("v_mfma_f32_32x32x16_bf16 %0, %1, %2, %0" : "+v"(acc) : "v"(aw[kt]), "v"(bfrag));
    }
#pragma unroll
    for (int kt = 0; kt < 12; ++kt) {
      asm("v_mfma_f32_32x32x16_bf16 %0, %1, %2, %0" : "+v"(acc) : "v"(aw[32 + kt]), "v"(xf[kt]));
    }
    asm volatile("s_nop 7\ns_nop 7\ns_nop 7");

    // ---- pointwise LSTM cell directly on accumulators
    // acc[q]=i, acc[4+q]=f, acc[8+q]=g, acc[12+q]=o for j=jme+q, b=bb_
    {
      u16* dstT = hb_dT + (par ^ 1) * 32768;
      u32 hp0 = 0, hp1 = 0;
#pragma unroll
      for (int q = 0; q < 4; ++q) {
        float gi = acc[q] + bI[q];
        float gf = acc[4 + q] + bF[q];
        float gg = acc[8 + q] + bG[q];
        float go = acc[12 + q] + bO[q];
        float cn = sigm(gf) * creg[q] + sigm(gi) * tanhx(gg);
        creg[q] = cn;
        float h = sigm(go) * tanhx(cn);
        u32 u = __float_as_uint(h); u += 0x7fffu + ((u >> 16) & 1u);
        u32 h16 = u >> 16;
        if (q == 0) hp0 = h16;
        else if (q == 1) hp0 |= h16 << 16;
        else if (q == 2) hp1 = h16;
        else hp1 |= h16 << 16;
      }
      u32x2 hv; hv[0] = hp0; hv[1] = hp1;
      stg8_l2(dstT + bb_ * 512 + jme, hv);   // own-L2 exchange store
      *(u32x2*)(hl + bb_ * 16 + (jme - j0)) = hv;
    }

    // ---- drain exchange stores (L2 ack; prev step's hs stores acked by now),
    //      block barrier, publish flag, THEN the slow HBM hs store
    asm volatile("s_waitcnt vmcnt(0)" ::: "memory");
    __syncthreads();
    if (t != TT - 1 && tid == 0) stflag(myflags + slot * 2, t + 1);
    if (tid < 128) {
      int ob = tid >> 1, hf = tid & 1;
      u32x4 v = *(const u32x4*)(hl + ob * 16 + hf * 8);
      *(u32x4*)(hs + ((size_t)tx * 64 + ob) * 1024 + dir * 512 + j0 + hf * 8) = v;
    }
  }
}

// ---- 3. emission: feats[row=t*64+b][c] = hs_row . w_cls[c] + b_cls[c] ----
__global__ __launch_bounds__(256) void k_emis(const u16* __restrict__ hs,
                                              const float* __restrict__ wcls,
                                              const float* __restrict__ bcls,
                                              float* __restrict__ feats) {
  __shared__ float wl[10240];
  int tid = threadIdx.x;
  for (int i = tid; i < 10240; i += 256) wl[i] = wcls[i];
  __syncthreads();
  int row = blockIdx.x * 256 + tid;
  const u16* hrow = hs + (size_t)row * 1024;
  float acc[10];
#pragma unroll
  for (int c = 0; c < 10; ++c) acc[c] = bcls[c];
  for (int k0 = 0; k0 < 1024; k0 += 8) {
    u32x4 v = *(const u32x4*)(hrow + k0);
    float x0 = __uint_as_float(v[0] << 16);
    float x1 = __uint_as_float(v[0] & 0xffff0000u);
    float x2 = __uint_as_float(v[1] << 16);
    float x3 = __uint_as_float(v[1] & 0xffff0000u);
    float x4 = __uint_as_float(v[2] << 16);
    float x5 = __uint_as_float(v[2] & 0xffff0000u);
    float x6 = __uint_as_float(v[3] << 16);
    float x7 = __uint_as_float(v[3] & 0xffff0000u);
#pragma unroll
    for (int c = 0; c < 10; ++c) {
      const float* w = &wl[c * 1024 + k0];
      f32x4v wa = *(const f32x4v*)w;
      f32x4v wb = *(const f32x4v*)(w + 4);
      acc[c] += x0 * wa[0] + x1 * wa[1] + x2 * wa[2] + x3 * wa[3] +
                x4 * wb[0] + x5 * wb[1] + x6 * wb[2] + x7 * wb[3];
    }
  }
#pragma unroll
  for (int c = 0; c < 10; ++c) feats[(size_t)row * 10 + c] = acc[c];
}

// ---- 4. CRF forward + gold score, one wave per batch element ----
__global__ void k_crf(const float* __restrict__ feats, const float* __restrict__ trans,
                      const int* __restrict__ btag, float* __restrict__ res) {
  int b = blockIdx.x;
  int lane = threadIdx.x;
  float tr[10];
  int to = lane < 10 ? lane : 9;
#pragma unroll
  for (int f = 0; f < 10; ++f) tr[f] = trans[to * 10 + f];
  float al[10];
#pragma unroll
  for (int f = 0; f < 10; ++f) al[f] = (f == 8) ? 0.f : -10000.f;  // START_ID=8
  float fe_next = (lane < 10) ? feats[(size_t)b * 10 + lane] : 0.f;
  for (int t = 0; t < 512; ++t) {
    float fe = fe_next;
    if (t < 511)
      fe_next = (lane < 10) ? feats[((size_t)(t + 1) * 64 + b) * 10 + lane] : 0.f;
    float mx = -3.0e38f;
#pragma unroll
    for (int f = 0; f < 10; ++f) mx = fmaxf(mx, al[f] + tr[f]);
    float s = 0.f;
#pragma unroll
    for (int f = 0; f < 10; ++f) s += __expf(al[f] + tr[f] - mx);
    float an = mx + __logf(s) + fe;
#pragma unroll
    for (int f = 0; f < 10; ++f) al[f] = __shfl(an, f);
  }
  float mx = -3.0e38f;
#pragma unroll
  for (int f = 0; f < 10; ++f) mx = fmaxf(mx, al[f]);
  float s = 0.f;
#pragma unroll
  for (int f = 0; f < 10; ++f) s += __expf(al[f] - mx);
  float fwd = mx + __logf(s);
  // gold score
  float g = 0.f;
  for (int t = lane; t < 512; t += 64) {
    int tg = btag[b * 512 + t];
    int pv = (t == 0) ? 8 : btag[b * 512 + t - 1];
    g += trans[tg * 10 + pv] + feats[((size_t)t * 64 + b) * 10 + tg];
  }
#pragma unroll
  for (int off = 32; off > 0; off >>= 1) g += __shfl_down(g, off);
  if (lane == 0) res[b] = fwd - g;
}

// ---- 5. final reduce ----
__global__ void k_fin(const float* __restrict__ res, float* __restrict__ out) {
  float v = res[threadIdx.x];
#pragma unroll
  for (int off = 32; off > 0; off >>= 1) v += __shfl_down(v, off);
  if (threadIdx.x == 0) out[0] = v * (1.f / 64.f);
}

extern "C" void kernel_launch(void* const* d_in, const int* in_sizes, int n_in,
                              void* d_out, int out_size, void* d_ws, size_t ws_size,
                              hipStream_t stream) {
  (void)in_sizes; (void)n_in; (void)out_size;
  if (ws_size < WS_NEED) return;  // visible failure instead of OOB

  const int* bdata = (const int*)d_in[0];
  const int* brad  = (const int*)d_in[1];
  const int* btag  = (const int*)d_in[2];
  const float* cemb = (const float*)d_in[3];
  const float* remb = (const float*)d_in[4];
  const float* wihf = (const float*)d_in[5];
  const float* whhf = (const float*)d_in[6];
  const float* bf   = (const float*)d_in[7];
  const float* wihb = (const float*)d_in[8];
  const float* whhb = (const float*)d_in[9];
  const float* bb   = (const float*)d_in[10];
  const float* wcls = (const float*)d_in[11];
  const float* bcls = (const float*)d_in[12];
  const float* trans = (const float*)d_in[13];

  char* ws = (char*)d_ws;
  u16* embX = (u16*)(ws + OFF_EMBX);
  u16* hs   = (u16*)(ws + OFF_HS);
  u16* hbuf = (u16*)(ws + OFF_HBUF);
  int* flags = (int*)(ws + OFF_BAR);
  float* feats = (float*)(ws + OFF_FEAT);
  float* res = (float*)(ws + OFF_RES);

  // zero h0 (both dirs, both parities) + ready-flags + claim counters
  hipMemsetAsync(ws + OFF_HBUF, 0, 262144 + 768, stream);

  k_embed<<<512, 256, 0, stream>>>(bdata, brad, cemb, remb, embX);
  k_lstm<<<512, 256, 0, stream>>>(embX, hbuf, hs, wihf, whhf, bf, wihb, whhb, bb, flags);
  k_emis<<<128, 256, 0, stream>>>(hs, wcls, bcls, feats);
  k_crf<<<64, 64, 0, stream>>>(feats, trans, btag, res);
  k_fin<<<1, 64, 0, stream>>>(res, (float*)d_out);
}